// Round 9
// baseline (80370.709 us; speedup 1.0000x reference)
//
#include <hip/hip_runtime.h>
#include <math.h>

#define Bsz  128
#define Lseq 256
#define Hdim 512
#define G4   2048
#define ROWS 4
#define NWGS (Bsz / ROWS)       // 32 workgroups per step
#define OUTHALF (Bsz * Lseq * 2) // 65536: planar split re | im

struct SArgs {
  const float *x, *Wx0, *Wh0, *b0, *Wx1, *Wh1, *b1;
  const float *Wr1, *br1, *Wr2, *br2, *Wi1, *bi1, *Wi2, *bi2;
  float *H0, *H1, *C0, *C1;     // [128][512] each, single-buffered
  float *out;                   // f32, PLANAR: [re (B,L,2)][im (B,L,2)]
};

__device__ __forceinline__ float sigf(float z) { return 1.f / (1.f + expf(-z)); }

// One timestep, fully fused: layer0 -> layer1 -> MLP for ROWS batch rows per wg.
// No cross-wg communication; steps are ordered by kernel boundaries on the stream.
__global__ void __launch_bounds__(256) step_fused(SArgs A, int t) {
  const int wg  = blockIdx.x;
  const int tid = threadIdx.x;          // 0..255
  const int b0r = wg * ROWS;

  __shared__ float h0p[ROWS][Hdim];     // h0[t-1]
  __shared__ float h1p[ROWS][Hdim];     // h1[t-1]
  __shared__ float h0n[ROWS][Hdim];     // h0[t]
  __shared__ float h1n[ROWS][Hdim];     // h1[t]

  for (int e = tid; e < ROWS * Hdim; e += 256) {
    int r = e >> 9, k = e & 511;
    h0p[r][k] = A.H0[(b0r + r) * Hdim + k];
    h1p[r][k] = A.H1[(b0r + r) * Hdim + k];
  }
  __syncthreads();

  // Thread tid owns gate-columns col = tid + 256*(q&1) + 512*(q>>1), q=0..7:
  // for h-cols {tid, tid+256}, all four gates (i,f,g,o) are thread-local.

  // ---------------- layer 0: z0 = onehot(x_t)@Wx0 + h0p@Wh0 + b0 ----------------
  {
    float acc[ROWS][8];
#pragma unroll
    for (int r = 0; r < ROWS; ++r)
#pragma unroll
      for (int q = 0; q < 8; ++q) acc[r][q] = 0.f;

    for (int k = 0; k < Hdim; ++k) {
      float a[ROWS];
#pragma unroll
      for (int r = 0; r < ROWS; ++r) a[r] = h0p[r][k];
      const float* wrow = A.Wh0 + (size_t)k * G4 + tid;
#pragma unroll
      for (int q = 0; q < 8; ++q) {
        float wv = wrow[256 * (q & 1) + 512 * (q >> 1)];
#pragma unroll
        for (int r = 0; r < ROWS; ++r) acc[r][q] += a[r] * wv;
      }
    }

#pragma unroll
    for (int r = 0; r < ROWS; ++r) {
      float xv = A.x[(b0r + r) * Lseq + t];
      int  xs  = (xv > 0.f) ? 1 : 0;
#pragma unroll
      for (int s = 0; s < 2; ++s) {
        int hcol = tid + 256 * s;
        float zi = acc[r][0 + s] + A.Wx0[xs * G4 + 0 * Hdim + hcol] + A.b0[0 * Hdim + hcol];
        float zf = acc[r][2 + s] + A.Wx0[xs * G4 + 1 * Hdim + hcol] + A.b0[1 * Hdim + hcol];
        float zg = acc[r][4 + s] + A.Wx0[xs * G4 + 2 * Hdim + hcol] + A.b0[2 * Hdim + hcol];
        float zo = acc[r][6 + s] + A.Wx0[xs * G4 + 3 * Hdim + hcol] + A.b0[3 * Hdim + hcol];
        float c  = A.C0[(b0r + r) * Hdim + hcol];
        c = sigf(zf) * c + sigf(zi) * tanhf(zg);
        float hv = sigf(zo) * tanhf(c);
        A.C0[(b0r + r) * Hdim + hcol] = c;
        h0n[r][hcol] = hv;
        A.H0[(b0r + r) * Hdim + hcol] = hv;
      }
    }
  }
  __syncthreads();

  // ---------------- layer 1: z1 = relu(h0n)@Wx1 + h1p@Wh1 + b1 ----------------
  {
    float acc[ROWS][8];
#pragma unroll
    for (int r = 0; r < ROWS; ++r)
#pragma unroll
      for (int q = 0; q < 8; ++q) acc[r][q] = 0.f;

    for (int k = 0; k < Hdim; ++k) {
      float a0[ROWS], a1[ROWS];
#pragma unroll
      for (int r = 0; r < ROWS; ++r) {
        a0[r] = fmaxf(h0n[r][k], 0.f);
        a1[r] = h1p[r][k];
      }
      const float* wxrow = A.Wx1 + (size_t)k * G4 + tid;
      const float* whrow = A.Wh1 + (size_t)k * G4 + tid;
#pragma unroll
      for (int q = 0; q < 8; ++q) {
        int off = 256 * (q & 1) + 512 * (q >> 1);
        float wx = wxrow[off];
        float wh = whrow[off];
#pragma unroll
        for (int r = 0; r < ROWS; ++r) acc[r][q] += a0[r] * wx + a1[r] * wh;
      }
    }

#pragma unroll
    for (int r = 0; r < ROWS; ++r) {
#pragma unroll
      for (int s = 0; s < 2; ++s) {
        int hcol = tid + 256 * s;
        float zi = acc[r][0 + s] + A.b1[0 * Hdim + hcol];
        float zf = acc[r][2 + s] + A.b1[1 * Hdim + hcol];
        float zg = acc[r][4 + s] + A.b1[2 * Hdim + hcol];
        float zo = acc[r][6 + s] + A.b1[3 * Hdim + hcol];
        float c  = A.C1[(b0r + r) * Hdim + hcol];
        c = sigf(zf) * c + sigf(zi) * tanhf(zg);
        float hv = sigf(zo) * tanhf(c);
        A.C1[(b0r + r) * Hdim + hcol] = c;
        h1n[r][hcol] = hv;
        A.H1[(b0r + r) * Hdim + hcol] = hv;
      }
    }
  }
  __syncthreads();

  // ---------------- MLP head: wave v handles batch row b0r+v ----------------
  {
    const int wv = tid >> 6;            // 0..3
    const int lane = tid & 63;
    float pr[10], pi[10];
#pragma unroll
    for (int j = 0; j < 10; ++j) { pr[j] = 0.f; pi[j] = 0.f; }
#pragma unroll
    for (int i2 = 0; i2 < 8; ++i2) {
      int k = (i2 << 6) + lane;         // 0..511
      float hv = fmaxf(h1n[wv][k], 0.f);
#pragma unroll
      for (int j = 0; j < 10; ++j) {
        pr[j] += hv * A.Wr1[k * 10 + j];
        pi[j] += hv * A.Wi1[k * 10 + j];
      }
    }
#pragma unroll
    for (int j = 0; j < 10; ++j)
#pragma unroll
      for (int off = 32; off >= 1; off >>= 1) {
        pr[j] += __shfl_xor(pr[j], off);
        pi[j] += __shfl_xor(pi[j], off);
      }
    if (lane == 0) {
      const int b = b0r + wv;
      float rsum[2] = {A.br2[0], A.br2[1]};
      float isum[2] = {A.bi2[0], A.bi2[1]};
#pragma unroll
      for (int j = 0; j < 10; ++j) {
        float ar = fmaxf(pr[j] + A.br1[j], 0.f);
        rsum[0] += ar * A.Wr2[j * 2];
        rsum[1] += ar * A.Wr2[j * 2 + 1];
        float ai = fmaxf(pi[j] + A.bi1[j], 0.f);
        isum[0] += ai * A.Wi2[j * 2];
        isum[1] += ai * A.Wi2[j * 2 + 1];
      }
      // LAYOUT: f32 PLANAR — re block [B,L,2] then im block [B,L,2]
#pragma unroll
      for (int m = 0; m < 2; ++m) {
        float im = 3.14159265358979323846f * (isum[m] / (1.f + fabsf(isum[m])));
        float sv, cv;
        sincosf(im, &sv, &cv);
        const int c = (b * Lseq + t) * 2 + m;
        A.out[c]           = rsum[m] * cv;   // real
        A.out[OUTHALF + c] = rsum[m] * sv;   // imag
      }
    }
  }
}

extern "C" void kernel_launch(void* const* d_in, const int* in_sizes, int n_in,
                              void* d_out, int out_size, void* d_ws, size_t ws_size,
                              hipStream_t stream) {
  // Input pointers in setup_inputs() dict order; defend against an
  // alphabetically-sorted harness order via the in_sizes signature
  // (x must have 32768 elements; sorted order would put Wh0 (1048576) first).
  const float* P[15];
  for (int i = 0; i < 15; ++i) P[i] = (const float*)d_in[i];
  if (in_sizes[0] != Bsz * Lseq) {
    // sorted: Wh0,Wh1,Wi1,Wi2,Wr1,Wr2,Wx0,Wx1,b0,b1,bi1,bi2,br1,br2,x
    // dict-order index -> sorted position:
    static const int m_[15] = {14, 6, 0, 8, 7, 1, 9, 4, 12, 5, 13, 2, 10, 3, 11};
    for (int i = 0; i < 15; ++i) P[i] = (const float*)d_in[m_[i]];
  }

  SArgs a;
  a.x   = P[0];
  a.Wx0 = P[1];
  a.Wh0 = P[2];
  a.b0  = P[3];
  a.Wx1 = P[4];
  a.Wh1 = P[5];
  a.b1  = P[6];
  a.Wr1 = P[7];
  a.br1 = P[8];
  a.Wr2 = P[9];
  a.br2 = P[10];
  a.Wi1 = P[11];
  a.bi1 = P[12];
  a.Wi2 = P[13];
  a.bi2 = P[14];

  float* ws = (float*)d_ws;
  a.H0 = ws;
  a.H1 = ws + (size_t)Bsz * Hdim;
  a.C0 = ws + (size_t)2 * Bsz * Hdim;
  a.C1 = ws + (size_t)3 * Bsz * Hdim;
  a.out = (float*)d_out;

  // zero recurrent state every call (graph-replay safe)
  hipMemsetAsync(ws, 0, (size_t)4 * Bsz * Hdim * sizeof(float), stream);

  for (int t = 0; t < Lseq; ++t) {
    step_fused<<<dim3(NWGS), dim3(256), 0, stream>>>(a, t);
  }
}

// Round 10
// 27028.549 us; speedup vs baseline: 2.9735x; 2.9735x over previous
//
#include <hip/hip_runtime.h>
#include <math.h>

#define Bsz  128
#define Lseq 256
#define Hdim 512
#define G4   2048
#define NWG  256
#define NT   256
#define RB   32      // batch rows per wg
#define HC   8       // h-cols per wg
#define LHP  516     // padded LDS row stride (floats)
#define OUTHALF (Bsz * Lseq * 2)   // 65536: planar split re | im

#define LH_ELEMS   (RB * LHP)                 // 16512
#define ZRED_ELEMS (RB * 33)                  // 1056: [row][gatecol 0..31], pad 33
#define MLP_ELEMS  80
#define LDS_FLOATS (2 * LH_ELEMS + ZRED_ELEMS + MLP_ELEMS)  // 34160
#define LDS_BYTES  (LDS_FLOATS * 4)           // 136,640 B < 160 KiB

struct PArgs {
  const float *x, *Wx0, *Wh0, *b0, *Wx1, *Wh1, *b1;   // original layouts [K][4H]
  const float *Wr1, *br1, *Wr2, *br2, *Wi1, *bi1, *Wi2, *bi2;
  float *H0, *H1;                             // double-buffered [2][128][512]
  int   *flags;
  float *out;                                 // f32 PLANAR: [re (B,L,2)][im (B,L,2)]
};

__device__ __forceinline__ float sigf(float z) {
  return 1.f / (1.f + expf(-z));
}

__global__ void __launch_bounds__(NT, 1) lstm_persist(PArgs A) {
  const int w    = blockIdx.x;
  const int tid  = threadIdx.x;
  const int bg   = w >> 6;              // batch group 0..3
  const int cs   = w & 63;              // column slice 0..63
  const int r0   = bg * RB;
  const int c0   = cs * HC;
  const int wv   = tid >> 6;            // wave 0..3 (MLP partials)
  const int lane = tid & 63;
  // GEMM mapping: thread = (quad q, row rr). quad q -> gate g=q>>1, 4 gate-cols.
  const int q    = tid >> 5;            // 0..7
  const int rr   = tid & 31;            // 0..31
  const int gq   = (q >> 1) * Hdim + c0 + (q & 1) * 4;  // global gate-col quad base
  // cell mapping: thread = (row rr2, h-col hcc)
  const int rr2  = tid >> 3;            // 0..31
  const int hcc  = tid & 7;             // 0..7

  extern __shared__ float lds[];
  float* lh0  = lds;                    // h0[p-1] staged, rows r0..r0+31
  float* lh1  = lds + LH_ELEMS;         // h1[p-2] staged
  float* zred = lds + 2 * LH_ELEMS;     // [32 rows][33] gate-col partials
  float* mlpb = zred + ZRED_ELEMS;      // [4 waves][20]

  // per-thread constants (cell mapping)
  float b0g[4], b1g[4], wx0a[4], wx0b[4];
#pragma unroll
  for (int g = 0; g < 4; ++g) {
    int gc = g * Hdim + c0 + hcc;
    b0g[g]  = A.b0[gc];
    b1g[g]  = A.b1[gc];
    wx0a[g] = A.Wx0[gc];        // one-hot row 0 (x = -1)
    wx0b[g] = A.Wx0[G4 + gc];   // one-hot row 1 (x = +1)
  }
  float c0s = 0.f, c1s = 0.f;   // cell states live in registers

  // weight quad-column pointers (float4 rows, stride 512 float4s = 2048 floats)
  const float4* Wx1q = (const float4*)(A.Wx1 + gq);
  const float4* Wh1q = (const float4*)(A.Wh1 + gq);
  const float4* Wh0q = (const float4*)(A.Wh0 + gq);

  for (int p = 0; p <= Lseq + 1; ++p) {
    // ---------- stage h0[p-1], h1[p-2] into LDS (agent-coherent 8B loads) ----------
    const unsigned long long* h0src8 =
      (const unsigned long long*)(A.H0 + (size_t)((p + 1) & 1) * (Bsz * Hdim) + (size_t)r0 * Hdim);
    const unsigned long long* h1src8 =
      (const unsigned long long*)(A.H1 + (size_t)(p & 1) * (Bsz * Hdim) + (size_t)r0 * Hdim);
#pragma unroll
    for (int it = 0; it < 32; ++it) {
      int e = it * NT + tid;                  // 0..8191 (32 rows x 256 8B-chunks)
      int row = e >> 8, c2 = e & 255;
      unsigned long long v0 = __hip_atomic_load(&h0src8[row * 256 + c2],
                                                __ATOMIC_RELAXED, __HIP_MEMORY_SCOPE_AGENT);
      unsigned long long v1 = __hip_atomic_load(&h1src8[row * 256 + c2],
                                                __ATOMIC_RELAXED, __HIP_MEMORY_SCOPE_AGENT);
      *(unsigned long long*)&lh0[row * LHP + c2 * 2] = v0;
      *(unsigned long long*)&lh1[row * LHP + c2 * 2] = v1;
    }
    __syncthreads();                          // sync A

    const bool doL1  = (p >= 1 && p <= Lseq); // compute h1[p-1]
    const bool doL0  = (p < Lseq);            // compute h0[p]
    const bool doMLP = (p >= 2 && cs < 32);   // out[p-2], row r0+cs

    // ---------- layer1 GEMM: z1[rr][quad] = relu(h0)@Wx1 + h1@Wh1 ----------
    if (doL1) {
      float4 acc = {0.f, 0.f, 0.f, 0.f};
#pragma unroll 2
      for (int k = 0; k < Hdim; k += 4) {
        float4 a0 = *(const float4*)&lh0[rr * LHP + k];
        float4 a1 = *(const float4*)&lh1[rr * LHP + k];
        a0.x = fmaxf(a0.x, 0.f); a0.y = fmaxf(a0.y, 0.f);
        a0.z = fmaxf(a0.z, 0.f); a0.w = fmaxf(a0.w, 0.f);
        float av[4] = {a0.x, a0.y, a0.z, a0.w};
        float hv[4] = {a1.x, a1.y, a1.z, a1.w};
#pragma unroll
        for (int kk = 0; kk < 4; ++kk) {
          float4 wx = Wx1q[(k + kk) * (G4 / 4)];
          float4 wh = Wh1q[(k + kk) * (G4 / 4)];
          acc.x += av[kk] * wx.x + hv[kk] * wh.x;
          acc.y += av[kk] * wx.y + hv[kk] * wh.y;
          acc.z += av[kk] * wx.z + hv[kk] * wh.z;
          acc.w += av[kk] * wx.w + hv[kk] * wh.w;
        }
      }
      zred[rr * 33 + q * 4 + 0] = acc.x;
      zred[rr * 33 + q * 4 + 1] = acc.y;
      zred[rr * 33 + q * 4 + 2] = acc.z;
      zred[rr * 33 + q * 4 + 3] = acc.w;
    }

    // ---------- MLP partials (reads only lh1) ----------
    if (doMLP) {
      float pr[10], pi[10];
#pragma unroll
      for (int j = 0; j < 10; ++j) { pr[j] = 0.f; pi[j] = 0.f; }
#pragma unroll
      for (int i2 = 0; i2 < 2; ++i2) {
        int k = (wv << 7) + (i2 << 6) + lane;
        float hv = fmaxf(lh1[cs * LHP + k], 0.f);
#pragma unroll
        for (int j = 0; j < 10; ++j) {
          pr[j] += hv * A.Wr1[k * 10 + j];
          pi[j] += hv * A.Wi1[k * 10 + j];
        }
      }
#pragma unroll
      for (int j = 0; j < 10; ++j)
#pragma unroll
        for (int off = 32; off >= 1; off >>= 1) {
          pr[j] += __shfl_xor(pr[j], off);
          pi[j] += __shfl_xor(pi[j], off);
        }
      if (lane == 0) {
#pragma unroll
        for (int j = 0; j < 10; ++j) { mlpb[wv * 20 + j] = pr[j]; mlpb[wv * 20 + 10 + j] = pi[j]; }
      }
    }
    __syncthreads();                          // sync B

    // ---------- layer1 cell update ----------
    if (doL1) {
      float z[4];
#pragma unroll
      for (int g = 0; g < 4; ++g)
        z[g] = zred[rr2 * 33 + g * 8 + hcc] + b1g[g];
      float ig = sigf(z[0]), fg = sigf(z[1]), gg = tanhf(z[2]), og = sigf(z[3]);
      c1s = fg * c1s + ig * gg;
      float hv = og * tanhf(c1s);
      float* H1w = A.H1 + (size_t)((p + 1) & 1) * (Bsz * Hdim);
      __hip_atomic_store(&H1w[(r0 + rr2) * Hdim + c0 + hcc], hv,
                         __ATOMIC_RELEASE, __HIP_MEMORY_SCOPE_AGENT);
    }
    __syncthreads();                          // sync C (zred free)

    // ---------- layer0 GEMM: z0[rr][quad] = h0 @ Wh0 ----------
    if (doL0) {
      float4 acc = {0.f, 0.f, 0.f, 0.f};
#pragma unroll 2
      for (int k = 0; k < Hdim; k += 4) {
        float4 a0 = *(const float4*)&lh0[rr * LHP + k];
        float av[4] = {a0.x, a0.y, a0.z, a0.w};
#pragma unroll
        for (int kk = 0; kk < 4; ++kk) {
          float4 wc = Wh0q[(k + kk) * (G4 / 4)];
          acc.x += av[kk] * wc.x;
          acc.y += av[kk] * wc.y;
          acc.z += av[kk] * wc.z;
          acc.w += av[kk] * wc.w;
        }
      }
      zred[rr * 33 + q * 4 + 0] = acc.x;
      zred[rr * 33 + q * 4 + 1] = acc.y;
      zred[rr * 33 + q * 4 + 2] = acc.z;
      zred[rr * 33 + q * 4 + 3] = acc.w;
    }
    __syncthreads();                          // sync D

    // ---------- layer0 cell update ----------
    if (doL0) {
      float xv = A.x[(r0 + rr2) * Lseq + p];
      float z[4];
#pragma unroll
      for (int g = 0; g < 4; ++g)
        z[g] = zred[rr2 * 33 + g * 8 + hcc] + b0g[g] + (xv > 0.f ? wx0b[g] : wx0a[g]);
      float ig = sigf(z[0]), fg = sigf(z[1]), gg = tanhf(z[2]), og = sigf(z[3]);
      c0s = fg * c0s + ig * gg;
      float hv = og * tanhf(c0s);
      float* H0w = A.H0 + (size_t)(p & 1) * (Bsz * Hdim);
      __hip_atomic_store(&H0w[(r0 + rr2) * Hdim + c0 + hcc], hv,
                         __ATOMIC_RELEASE, __HIP_MEMORY_SCOPE_AGENT);
    }

    // ---------- MLP epilogue + output (f32 PLANAR re|im) ----------
    if (doMLP && tid == 0) {
      const int t = p - 2, b = r0 + cs;
      float rsum[2] = {A.br2[0], A.br2[1]};
      float isum[2] = {A.bi2[0], A.bi2[1]};
#pragma unroll
      for (int j = 0; j < 10; ++j) {
        float ar = mlpb[j] + mlpb[20 + j] + mlpb[40 + j] + mlpb[60 + j] + A.br1[j];
        ar = fmaxf(ar, 0.f);
        rsum[0] += ar * A.Wr2[j * 2];
        rsum[1] += ar * A.Wr2[j * 2 + 1];
        float ai = mlpb[10 + j] + mlpb[30 + j] + mlpb[50 + j] + mlpb[70 + j] + A.bi1[j];
        ai = fmaxf(ai, 0.f);
        isum[0] += ai * A.Wi2[j * 2];
        isum[1] += ai * A.Wi2[j * 2 + 1];
      }
#pragma unroll
      for (int m = 0; m < 2; ++m) {
        float im = 3.14159265358979323846f * (isum[m] / (1.f + fabsf(isum[m])));
        float sv, cv;
        sincosf(im, &sv, &cv);
        const int c = (b * Lseq + t) * 2 + m;
        A.out[c]           = rsum[m] * cv;   // real
        A.out[OUTHALF + c] = rsum[m] * sv;   // imag
      }
    }

    // ---------- grid barrier: flags, each thread polls one wg ----------
    __syncthreads();
    if (tid == 0) {
      __threadfence();
      __hip_atomic_store(&A.flags[w], p + 1, __ATOMIC_RELEASE, __HIP_MEMORY_SCOPE_AGENT);
    }
    while (__hip_atomic_load(&A.flags[tid], __ATOMIC_RELAXED, __HIP_MEMORY_SCOPE_AGENT) < p + 1) {
      __builtin_amdgcn_s_sleep(1);
    }
    __syncthreads();
  }
}

extern "C" void kernel_launch(void* const* d_in, const int* in_sizes, int n_in,
                              void* d_out, int out_size, void* d_ws, size_t ws_size,
                              hipStream_t stream) {
  // Input pointers in setup_inputs() dict order; defend against an
  // alphabetically-sorted harness order via the in_sizes signature.
  const float* P[15];
  for (int i = 0; i < 15; ++i) P[i] = (const float*)d_in[i];
  if (in_sizes[0] != Bsz * Lseq) {
    static const int m_[15] = {14, 6, 0, 8, 7, 1, 9, 4, 12, 5, 13, 2, 10, 3, 11};
    for (int i = 0; i < 15; ++i) P[i] = (const float*)d_in[m_[i]];
  }

  PArgs a;
  a.x   = P[0];
  a.Wx0 = P[1];
  a.Wh0 = P[2];
  a.b0  = P[3];
  a.Wx1 = P[4];
  a.Wh1 = P[5];
  a.b1  = P[6];
  a.Wr1 = P[7];
  a.br1 = P[8];
  a.Wr2 = P[9];
  a.br2 = P[10];
  a.Wi1 = P[11];
  a.bi1 = P[12];
  a.Wi2 = P[13];
  a.bi2 = P[14];

  // workspace: H0 (2 parities) + H1 (2 parities) + flags = ~1.05 MB
  float* ws = (float*)d_ws;
  a.H0 = ws;
  a.H1 = ws + 2 * Bsz * Hdim;
  a.flags = (int*)(ws + 4 * Bsz * Hdim);
  a.out = (float*)d_out;

  // zero H state (both parities) + flags every call (replay-safe)
  hipMemsetAsync(ws, 0, (size_t)(4 * Bsz * Hdim) * sizeof(float) + NWG * sizeof(int), stream);

  hipFuncSetAttribute((const void*)lstm_persist,
                      hipFuncAttributeMaxDynamicSharedMemorySize, LDS_BYTES);
  // plain launch: 256 wgs, 1 wg/CU (forced by LDS + launch_bounds) on 256 CUs
  lstm_persist<<<dim3(NWG), dim3(NT), LDS_BYTES, stream>>>(a);
}

// Round 11
// 19089.034 us; speedup vs baseline: 4.2103x; 1.4159x over previous
//
#include <hip/hip_runtime.h>
#include <math.h>

#define Bsz  128
#define Lseq 256
#define Hdim 512
#define G4   2048
#define NWG  256
#define NT   512
#define RB   32      // batch rows per wg
#define LHP  516     // padded LDS row stride (floats), 16B-aligned rows
#define OUTHALF (Bsz * Lseq * 2)   // 65536: planar split re | im

#define LH_ELEMS   (RB * LHP)                 // 16512
#define ZRED_ELEMS (2 * 2 * RB * 33)          // 4224: [kh][layer][row][col(33 pad)]
#define MLP_ELEMS  80
#define LDS_FLOATS (2 * LH_ELEMS + ZRED_ELEMS + MLP_ELEMS)  // 37328
#define LDS_BYTES  (LDS_FLOATS * 4)           // 149,312 B < 160 KiB -> 1 wg/CU

#define ZI(khh, ly, row, col) (((((khh)*2+(ly))*RB + (row))*33) + (col))

struct PArgs {
  const float *x, *Wx0, *Wh0, *b0, *Wx1, *Wh1, *b1;   // original layouts [K][4H]
  const float *Wr1, *br1, *Wr2, *br2, *Wi1, *bi1, *Wi2, *bi2;
  float *H0, *H1;                             // double-buffered [2][128][512]
  int   *flags;
  float *out;                                 // f32 PLANAR: [re (B,L,2)][im (B,L,2)]
};

__device__ __forceinline__ float sigf(float z) {
  return 1.f / (1.f + expf(-z));
}

__global__ void __launch_bounds__(NT, 1) lstm_persist(PArgs A) {
  const int w    = blockIdx.x;
  const int tid  = threadIdx.x;
  // XCD-aware mapping (blockIdx -> XCD is round-robin %8 on MI355X):
  // XCD x hosts cs in [8x, 8x+8) -> 64 contiguous h-cols -> 1.5 MB weight
  // slice per XCD, L2-resident across all 258 phases.
  const int cs   = (w & 7) * 8 + ((w >> 3) & 7);  // 0..63
  const int bg   = w >> 6;                         // 0..3
  const int r0   = bg * RB;
  const int c0   = cs * 8;
  // GEMM mapping: thread = (k-half kh, col-quad q, row rr)
  const int q    = (tid >> 5) & 7;      // 0..7
  const int rr   = tid & 31;            // 0..31
  const int kh   = tid >> 8;            // 0..1
  const int kbase = kh << 8;            // 0 or 256
  const int gq   = (q >> 1) * Hdim + c0 + (q & 1) * 4;
  // cell mapping (tid < 256): thread = (row rr2, h-col hcc)
  const int rr2  = (tid >> 3) & 31;
  const int hcc  = tid & 7;
  // MLP mapping (tid < 256)
  const int wv   = (tid >> 6) & 3;
  const int lane = tid & 63;

  extern __shared__ float lds[];
  float* lh0  = lds;                    // h0[p-1], rows r0..r0+31
  float* lh1  = lds + LH_ELEMS;         // h1[p-2]
  float* zred = lds + 2 * LH_ELEMS;     // [2][2][32][33]
  float* mlpb = zred + ZRED_ELEMS;      // [4 waves][20]

  // per-thread cell constants (tid < 256 only)
  float b0g[4], b1g[4], wx0a[4], wx0b[4];
  if (tid < 256) {
#pragma unroll
    for (int g = 0; g < 4; ++g) {
      int gc = g * Hdim + c0 + hcc;
      b0g[g]  = A.b0[gc];
      b1g[g]  = A.b1[gc];
      wx0a[g] = A.Wx0[gc];        // one-hot row 0 (x = -1)
      wx0b[g] = A.Wx0[G4 + gc];   // one-hot row 1 (x = +1)
    }
  }
  float c0s = 0.f, c1s = 0.f;   // cell states in registers (tid < 256)

  const float4* Wx1q = (const float4*)(A.Wx1 + gq);
  const float4* Wh1q = (const float4*)(A.Wh1 + gq);
  const float4* Wh0q = (const float4*)(A.Wh0 + gq);

  for (int p = 0; p <= Lseq + 1; ++p) {
    // ---------- stage h0[p-1], h1[p-2] into LDS (agent-coherent 8B loads) ----------
    const unsigned long long* h0src8 =
      (const unsigned long long*)(A.H0 + (size_t)((p + 1) & 1) * (Bsz * Hdim) + (size_t)r0 * Hdim);
    const unsigned long long* h1src8 =
      (const unsigned long long*)(A.H1 + (size_t)(p & 1) * (Bsz * Hdim) + (size_t)r0 * Hdim);
#pragma unroll
    for (int it = 0; it < 16; ++it) {
      int e = it * NT + tid;                  // 0..8191 (32 rows x 256 8B-chunks)
      int row = e >> 8, c2 = e & 255;
      unsigned long long v0 = __hip_atomic_load(&h0src8[row * 256 + c2],
                                                __ATOMIC_RELAXED, __HIP_MEMORY_SCOPE_AGENT);
      unsigned long long v1 = __hip_atomic_load(&h1src8[row * 256 + c2],
                                                __ATOMIC_RELAXED, __HIP_MEMORY_SCOPE_AGENT);
      *(unsigned long long*)&lh0[row * LHP + c2 * 2] = v0;
      *(unsigned long long*)&lh1[row * LHP + c2 * 2] = v1;
    }
    __syncthreads();                          // sync A

    const bool doL1  = (p >= 1 && p <= Lseq);
    const bool doL0  = (p < Lseq);
    const bool doMLP = (p >= 2 && cs < 32 && tid < 256);

    // ---------- fused GEMM over this thread's k-half ----------
    // z1 = relu(h0[p-1])@Wx1 + h1[p-2]@Wh1 ;  z0 = h0[p-1]@Wh0
    {
      float4 az1 = {0.f, 0.f, 0.f, 0.f};
      float4 az0 = {0.f, 0.f, 0.f, 0.f};
#pragma unroll 2
      for (int kk4 = 0; kk4 < 256; kk4 += 4) {
        const int k = kbase + kk4;
        float4 a0 = *(const float4*)&lh0[rr * LHP + k];
        float4 a1 = *(const float4*)&lh1[rr * LHP + k];
        float a0v[4] = {a0.x, a0.y, a0.z, a0.w};
        float arv[4] = {fmaxf(a0.x, 0.f), fmaxf(a0.y, 0.f), fmaxf(a0.z, 0.f), fmaxf(a0.w, 0.f)};
        float a1v[4] = {a1.x, a1.y, a1.z, a1.w};
#pragma unroll
        for (int kk = 0; kk < 4; ++kk) {
          float4 wx = Wx1q[(k + kk) * (G4 / 4)];
          float4 wh = Wh1q[(k + kk) * (G4 / 4)];
          float4 w0 = Wh0q[(k + kk) * (G4 / 4)];
          az1.x += arv[kk] * wx.x + a1v[kk] * wh.x;
          az1.y += arv[kk] * wx.y + a1v[kk] * wh.y;
          az1.z += arv[kk] * wx.z + a1v[kk] * wh.z;
          az1.w += arv[kk] * wx.w + a1v[kk] * wh.w;
          az0.x += a0v[kk] * w0.x;
          az0.y += a0v[kk] * w0.y;
          az0.z += a0v[kk] * w0.z;
          az0.w += a0v[kk] * w0.w;
        }
      }
      const int cq = q * 4;
      zred[ZI(kh, 1, rr, cq + 0)] = az1.x;
      zred[ZI(kh, 1, rr, cq + 1)] = az1.y;
      zred[ZI(kh, 1, rr, cq + 2)] = az1.z;
      zred[ZI(kh, 1, rr, cq + 3)] = az1.w;
      zred[ZI(kh, 0, rr, cq + 0)] = az0.x;
      zred[ZI(kh, 0, rr, cq + 1)] = az0.y;
      zred[ZI(kh, 0, rr, cq + 2)] = az0.z;
      zred[ZI(kh, 0, rr, cq + 3)] = az0.w;
    }

    // ---------- MLP partials (waves 0-3; reads only lh1) ----------
    if (doMLP) {
      float pr[10], pi[10];
#pragma unroll
      for (int j = 0; j < 10; ++j) { pr[j] = 0.f; pi[j] = 0.f; }
#pragma unroll
      for (int i2 = 0; i2 < 2; ++i2) {
        int k = (wv << 7) + (i2 << 6) + lane;
        float hv = fmaxf(lh1[cs * LHP + k], 0.f);
#pragma unroll
        for (int j = 0; j < 10; ++j) {
          pr[j] += hv * A.Wr1[k * 10 + j];
          pi[j] += hv * A.Wi1[k * 10 + j];
        }
      }
#pragma unroll
      for (int j = 0; j < 10; ++j)
#pragma unroll
        for (int off = 32; off >= 1; off >>= 1) {
          pr[j] += __shfl_xor(pr[j], off);
          pi[j] += __shfl_xor(pi[j], off);
        }
      if (lane == 0) {
#pragma unroll
        for (int j = 0; j < 10; ++j) { mlpb[wv * 20 + j] = pr[j]; mlpb[wv * 20 + 10 + j] = pi[j]; }
      }
    }
    __syncthreads();                          // sync B

    // ---------- cell updates (tid < 256) ----------
    if (tid < 256) {
      if (doL1) {
        float z[4];
#pragma unroll
        for (int g = 0; g < 4; ++g)
          z[g] = zred[ZI(0, 1, rr2, g * 8 + hcc)] + zred[ZI(1, 1, rr2, g * 8 + hcc)] + b1g[g];
        float ig = sigf(z[0]), fg = sigf(z[1]), gg = tanhf(z[2]), og = sigf(z[3]);
        c1s = fg * c1s + ig * gg;
        float hv = og * tanhf(c1s);
        float* H1w = A.H1 + (size_t)((p + 1) & 1) * (Bsz * Hdim);
        __hip_atomic_store(&H1w[(r0 + rr2) * Hdim + c0 + hcc], hv,
                           __ATOMIC_RELAXED, __HIP_MEMORY_SCOPE_AGENT);
      }
      if (doL0) {
        float xv = A.x[(r0 + rr2) * Lseq + p];
        float z[4];
#pragma unroll
        for (int g = 0; g < 4; ++g)
          z[g] = zred[ZI(0, 0, rr2, g * 8 + hcc)] + zred[ZI(1, 0, rr2, g * 8 + hcc)]
               + b0g[g] + (xv > 0.f ? wx0b[g] : wx0a[g]);
        float ig = sigf(z[0]), fg = sigf(z[1]), gg = tanhf(z[2]), og = sigf(z[3]);
        c0s = fg * c0s + ig * gg;
        float hv = og * tanhf(c0s);
        float* H0w = A.H0 + (size_t)(p & 1) * (Bsz * Hdim);
        __hip_atomic_store(&H0w[(r0 + rr2) * Hdim + c0 + hcc], hv,
                           __ATOMIC_RELAXED, __HIP_MEMORY_SCOPE_AGENT);
      }
    }

    // ---------- MLP epilogue + output (f32 PLANAR re|im) ----------
    if (doMLP && tid == 0) {
      const int t = p - 2, b = r0 + cs;
      float rsum[2] = {A.br2[0], A.br2[1]};
      float isum[2] = {A.bi2[0], A.bi2[1]};
#pragma unroll
      for (int j = 0; j < 10; ++j) {
        float ar = mlpb[j] + mlpb[20 + j] + mlpb[40 + j] + mlpb[60 + j] + A.br1[j];
        ar = fmaxf(ar, 0.f);
        rsum[0] += ar * A.Wr2[j * 2];
        rsum[1] += ar * A.Wr2[j * 2 + 1];
        float ai = mlpb[10 + j] + mlpb[30 + j] + mlpb[50 + j] + mlpb[70 + j] + A.bi1[j];
        ai = fmaxf(ai, 0.f);
        isum[0] += ai * A.Wi2[j * 2];
        isum[1] += ai * A.Wi2[j * 2 + 1];
      }
#pragma unroll
      for (int m = 0; m < 2; ++m) {
        float im = 3.14159265358979323846f * (isum[m] / (1.f + fabsf(isum[m])));
        float sv, cv;
        sincosf(im, &sv, &cv);
        const int c = (b * Lseq + t) * 2 + m;
        A.out[c]           = rsum[m] * cv;   // real
        A.out[OUTHALF + c] = rsum[m] * sv;   // imag
      }
    }

    // ---------- grid barrier (no threadfence: syncthreads drains vmcnt; ----------
    // ---------- release flag store orders; sc1 loads see coherence point) --------
    __syncthreads();
    if (tid == 0) {
      __hip_atomic_store(&A.flags[w], p + 1, __ATOMIC_RELEASE, __HIP_MEMORY_SCOPE_AGENT);
    }
    while (__hip_atomic_load(&A.flags[tid & 255], __ATOMIC_RELAXED, __HIP_MEMORY_SCOPE_AGENT) < p + 1) {
      __builtin_amdgcn_s_sleep(2);
    }
    __syncthreads();
  }
}

extern "C" void kernel_launch(void* const* d_in, const int* in_sizes, int n_in,
                              void* d_out, int out_size, void* d_ws, size_t ws_size,
                              hipStream_t stream) {
  // Input pointers in setup_inputs() dict order; defend against an
  // alphabetically-sorted harness order via the in_sizes signature.
  const float* P[15];
  for (int i = 0; i < 15; ++i) P[i] = (const float*)d_in[i];
  if (in_sizes[0] != Bsz * Lseq) {
    static const int m_[15] = {14, 6, 0, 8, 7, 1, 9, 4, 12, 5, 13, 2, 10, 3, 11};
    for (int i = 0; i < 15; ++i) P[i] = (const float*)d_in[m_[i]];
  }

  PArgs a;
  a.x   = P[0];
  a.Wx0 = P[1];
  a.Wh0 = P[2];
  a.b0  = P[3];
  a.Wx1 = P[4];
  a.Wh1 = P[5];
  a.b1  = P[6];
  a.Wr1 = P[7];
  a.br1 = P[8];
  a.Wr2 = P[9];
  a.br2 = P[10];
  a.Wi1 = P[11];
  a.bi1 = P[12];
  a.Wi2 = P[13];
  a.bi2 = P[14];

  // workspace: H0 (2 parities) + H1 (2 parities) + flags
  float* ws = (float*)d_ws;
  a.H0 = ws;
  a.H1 = ws + 2 * Bsz * Hdim;
  a.flags = (int*)(ws + 4 * Bsz * Hdim);
  a.out = (float*)d_out;

  // zero H state (both parities) + flags every call (replay-safe)
  hipMemsetAsync(ws, 0, (size_t)(4 * Bsz * Hdim) * sizeof(float) + NWG * sizeof(int), stream);

  hipFuncSetAttribute((const void*)lstm_persist,
                      hipFuncAttributeMaxDynamicSharedMemorySize, LDS_BYTES);
  // plain launch: 256 wgs, 1 wg/CU (forced by 149 KB LDS) on 256 CUs
  lstm_persist<<<dim3(NWG), dim3(NT), LDS_BYTES, stream>>>(a);
}